// Round 1
// 855.320 us; speedup vs baseline: 1.1911x; 1.1911x over previous
//
#include <hip/hip_runtime.h>
#include <math.h>

// Problem constants (B,H,S,D) = (2,16,2048,64), fp32 in, fp32 out.
constexpr int Bc = 2, Hc = 16, Sc = 2048, Dc = 64;
constexpr int BM = 64;   // q rows per block
constexpr int BN = 64;   // k rows per tile
constexpr int LDQ = 72;  // padded LDS stride for Qs/Ks/Ps (144B rows, 16B aligned)
constexpr int LDV = 72;  // padded kv-stride for transposed Vt[d][kv]
constexpr int NKT = Sc / BN;
constexpr float SCALE = 0.125f; // 1/sqrt(64)

typedef __bf16 bf16_t;
typedef __bf16 bf16x8 __attribute__((ext_vector_type(8)));
typedef __bf16 bf16x4 __attribute__((ext_vector_type(4)));
typedef float floatx4 __attribute__((ext_vector_type(4)));

#define MFMA16(a, b, c) __builtin_amdgcn_mfma_f32_16x16x32_bf16((a), (b), (c), 0, 0, 0)

__global__ __launch_bounds__(256, 2)
void sdpa_fused_kernel(const float* __restrict__ Q, const float* __restrict__ K,
                       const float* __restrict__ V, const int* __restrict__ Mask,
                       float* __restrict__ CtxOut, float* __restrict__ ProbOut)
{
    // Qs/Ks/Ps row-major [row][LDQ]; Vt transposed [d][LDV] so PV B-frags are b128 reads.
    __shared__ __align__(16) bf16_t Qs[BM * LDQ];
    __shared__ __align__(16) bf16_t Ks[BN * LDQ];
    __shared__ __align__(16) bf16_t Vt[Dc * LDV];
    __shared__ __align__(16) bf16_t Ps[BM * LDQ];  // wave w owns rows [16w, 16w+16)

    const int tid  = threadIdx.x;
    const int wave = tid >> 6;
    const int lane = tid & 63;
    const int quad = lane >> 4;
    const int l16  = lane & 15;

    const int qt    = blockIdx.x;       // q tile index
    const int bh    = blockIdx.y;       // b*H + h
    const int b     = bh >> 4;          // H = 16
    const int qbase = qt * BM;

    const float* Qp = Q + ((size_t)bh * Sc + qbase) * Dc;
    const float* Kp = K + (size_t)bh * Sc * Dc;
    const float* Vp = V + (size_t)bh * Sc * Dc;
    const int*   Mp = Mask + (size_t)b * Sc * Sc;
    float* Pg = ProbOut + (size_t)bh * Sc * Sc;
    float* Cg = CtxOut + ((size_t)bh * Sc + qbase) * Dc;

    // ---- stage Q tile (64x64 fp32 -> bf16 LDS) ----
    #pragma unroll
    for (int t = 0; t < 4; ++t) {
        int i = tid + t * 256;          // float4 index, 1024 total
        int r = i >> 4;                 // 16 float4 per row
        int c = (i & 15) << 2;
        float4 v = *reinterpret_cast<const float4*>(Qp + r * Dc + c);
        bf16x4 w; w[0] = (bf16_t)v.x; w[1] = (bf16_t)v.y; w[2] = (bf16_t)v.z; w[3] = (bf16_t)v.w;
        *reinterpret_cast<bf16x4*>(&Qs[r * LDQ + c]) = w;
    }
    __syncthreads();

    // Q A-fragments (hoisted; Qs never overwritten). A[m=l16][k=quad*8+j].
    const int qrow_lds = wave * 16 + l16;
    bf16x8 qa0 = *reinterpret_cast<const bf16x8*>(&Qs[qrow_lds * LDQ + quad * 8]);
    bf16x8 qa1 = *reinterpret_cast<const bf16x8*>(&Qs[qrow_lds * LDQ + 32 + quad * 8]);

    float m_i[4], l_i[4];
    #pragma unroll
    for (int r = 0; r < 4; ++r) { m_i[r] = -3.0e38f; l_i[r] = 0.f; }

    const int mrow0 = qbase + wave * 16 + quad * 4;  // + r = global q row of acc reg r
    // Hoisted row pointers: per-access addressing reduces to base + small imm.
    const int* mr[4]; float* pr[4];
    #pragma unroll
    for (int r = 0; r < 4; ++r) {
        mr[r] = Mp + (size_t)(mrow0 + r) * Sc;
        pr[r] = Pg + (size_t)(mrow0 + r) * Sc;
    }

    // ================= PASS 1: row max + sumexp (online) =================
    // Register-prefetch pipeline: tile kt+1's loads issue while kt computes.
    float4 kreg[4];
    #pragma unroll
    for (int t = 0; t < 4; ++t) {
        int i = tid + t * 256;
        kreg[t] = *reinterpret_cast<const float4*>(Kp + (i >> 4) * Dc + ((i & 15) << 2));
    }
    for (int kt = 0; kt < NKT; ++kt) {
        __syncthreads();  // previous tile's LDS reads complete
        #pragma unroll
        for (int t = 0; t < 4; ++t) {
            int i = tid + t * 256;
            int r = i >> 4;
            int c = (i & 15) << 2;
            bf16x4 w; w[0] = (bf16_t)kreg[t].x; w[1] = (bf16_t)kreg[t].y;
                      w[2] = (bf16_t)kreg[t].z; w[3] = (bf16_t)kreg[t].w;
            *reinterpret_cast<bf16x4*>(&Ks[r * LDQ + c]) = w;
        }
        if (kt + 1 < NKT) {
            const float* Kn = Kp + (size_t)(kt + 1) * BN * Dc;
            #pragma unroll
            for (int t = 0; t < 4; ++t) {
                int i = tid + t * 256;
                kreg[t] = *reinterpret_cast<const float4*>(Kn + (i >> 4) * Dc + ((i & 15) << 2));
            }
        }
        __syncthreads();

        const int kc = kt * BN + l16;
        // Issue mask loads before the MFMA cluster; latency hides under it.
        int mv[4][4];
        #pragma unroll
        for (int nt = 0; nt < 4; ++nt)
            #pragma unroll
            for (int r = 0; r < 4; ++r)
                mv[nt][r] = mr[r][kc + nt * 16];

        floatx4 acc[4];
        #pragma unroll
        for (int nt = 0; nt < 4; ++nt) acc[nt] = (floatx4){0.f, 0.f, 0.f, 0.f};
        #pragma unroll
        for (int nt = 0; nt < 4; ++nt) {
            const bf16_t* kr = &Ks[(nt * 16 + l16) * LDQ + quad * 8];
            bf16x8 kb0 = *reinterpret_cast<const bf16x8*>(kr);
            bf16x8 kb1 = *reinterpret_cast<const bf16x8*>(kr + 32);
            acc[nt] = MFMA16(qa0, kb0, acc[nt]);
            acc[nt] = MFMA16(qa1, kb1, acc[nt]);
        }
        #pragma unroll
        for (int nt = 0; nt < 4; ++nt) {
            #pragma unroll
            for (int r = 0; r < 4; ++r) {
                float sv = acc[nt][r] * SCALE;
                acc[nt][r] = mv[nt][r] ? sv : -1e9f;
            }
        }
        #pragma unroll
        for (int r = 0; r < 4; ++r) {
            float mx = fmaxf(fmaxf(acc[0][r], acc[1][r]), fmaxf(acc[2][r], acc[3][r]));
            #pragma unroll
            for (int off = 1; off < 16; off <<= 1) mx = fmaxf(mx, __shfl_xor(mx, off, 64));
            float mn = fmaxf(m_i[r], mx);
            float sum = __expf(acc[0][r] - mn) + __expf(acc[1][r] - mn) +
                        __expf(acc[2][r] - mn) + __expf(acc[3][r] - mn);
            #pragma unroll
            for (int off = 1; off < 16; off <<= 1) sum += __shfl_xor(sum, off, 64);
            l_i[r] = l_i[r] * __expf(m_i[r] - mn) + sum;
            m_i[r] = mn;
        }
    }

    float linv[4];
    #pragma unroll
    for (int r = 0; r < 4; ++r) linv[r] = 1.0f / l_i[r];

    floatx4 co[4];
    #pragma unroll
    for (int dt = 0; dt < 4; ++dt) co[dt] = (floatx4){0.f, 0.f, 0.f, 0.f};

    // ================= PASS 2: P = exp(s-m)/l, write P, PV MFMA =================
    // V prefetch uses row=lane so the transposed LDS writes (kv=lane) are
    // contiguous -> bank-conflict-free ds_write_b16. V tile is L2-hot (reused
    // by 32 q-blocks), so the scattered global pattern costs little and the
    // prefetch hides its latency.
    float4 vreg[4];
    #pragma unroll
    for (int t = 0; t < 4; ++t) {
        int i = tid + t * 256;
        kreg[t] = *reinterpret_cast<const float4*>(Kp + (i >> 4) * Dc + ((i & 15) << 2));
        vreg[t] = *reinterpret_cast<const float4*>(Vp + (size_t)lane * Dc + 4 * (4 * wave + t));
    }
    for (int kt = 0; kt < NKT; ++kt) {
        __syncthreads();  // previous tile's Ks/Vt reads complete
        #pragma unroll
        for (int t = 0; t < 4; ++t) {
            int i = tid + t * 256;
            int r = i >> 4;
            int c = (i & 15) << 2;
            bf16x4 w; w[0] = (bf16_t)kreg[t].x; w[1] = (bf16_t)kreg[t].y;
                      w[2] = (bf16_t)kreg[t].z; w[3] = (bf16_t)kreg[t].w;
            *reinterpret_cast<bf16x4*>(&Ks[r * LDQ + c]) = w;
            // transposed V write: Vt[d][kv], kv = lane contiguous per instruction
            const int d0 = 4 * (4 * wave + t);
            Vt[(d0 + 0) * LDV + lane] = (bf16_t)vreg[t].x;
            Vt[(d0 + 1) * LDV + lane] = (bf16_t)vreg[t].y;
            Vt[(d0 + 2) * LDV + lane] = (bf16_t)vreg[t].z;
            Vt[(d0 + 3) * LDV + lane] = (bf16_t)vreg[t].w;
        }
        if (kt + 1 < NKT) {
            const float* Kn = Kp + (size_t)(kt + 1) * BN * Dc;
            const float* Vn = Vp + (size_t)(kt + 1) * BN * Dc;
            #pragma unroll
            for (int t = 0; t < 4; ++t) {
                int i = tid + t * 256;
                kreg[t] = *reinterpret_cast<const float4*>(Kn + (i >> 4) * Dc + ((i & 15) << 2));
                vreg[t] = *reinterpret_cast<const float4*>(Vn + (size_t)lane * Dc + 4 * (4 * wave + t));
            }
        }
        __syncthreads();

        const int kc = kt * BN + l16;
        int mv[4][4];
        #pragma unroll
        for (int nt = 0; nt < 4; ++nt)
            #pragma unroll
            for (int r = 0; r < 4; ++r)
                mv[nt][r] = mr[r][kc + nt * 16];

        floatx4 acc[4];
        #pragma unroll
        for (int nt = 0; nt < 4; ++nt) acc[nt] = (floatx4){0.f, 0.f, 0.f, 0.f};
        #pragma unroll
        for (int nt = 0; nt < 4; ++nt) {
            const bf16_t* kr = &Ks[(nt * 16 + l16) * LDQ + quad * 8];
            bf16x8 kb0 = *reinterpret_cast<const bf16x8*>(kr);
            bf16x8 kb1 = *reinterpret_cast<const bf16x8*>(kr + 32);
            acc[nt] = MFMA16(qa0, kb0, acc[nt]);
            acc[nt] = MFMA16(qa1, kb1, acc[nt]);
        }
        #pragma unroll
        for (int nt = 0; nt < 4; ++nt) {
            #pragma unroll
            for (int r = 0; r < 4; ++r) {
                float sv = acc[nt][r] * SCALE;
                sv = mv[nt][r] ? sv : -1e9f;
                float p = __expf(sv - m_i[r]) * linv[r];
                // global P write: 16 lanes of a quad write 64B contiguous
                pr[r][kc + nt * 16] = p;
                // stage bf16 P for the PV A-fragment (wave-private rows)
                Ps[(wave * 16 + quad * 4 + r) * LDQ + nt * 16 + l16] = (bf16_t)p;
            }
        }
        // No barrier: Ps rows [16w,16w+16) are written and read only by wave w;
        // intra-wave ds_write -> ds_read ordering is enforced by lgkmcnt.
        #pragma unroll
        for (int ks = 0; ks < 2; ++ks) {
            bf16x8 pa = *reinterpret_cast<const bf16x8*>(
                &Ps[(wave * 16 + l16) * LDQ + ks * 32 + quad * 8]);
            #pragma unroll
            for (int dt = 0; dt < 4; ++dt) {
                // B-frag: V[kv = ks*32+quad*8+j][d = dt*16+l16] = Vt[d][kv], one b128
                bf16x8 vb = *reinterpret_cast<const bf16x8*>(
                    &Vt[(dt * 16 + l16) * LDV + ks * 32 + quad * 8]);
                co[dt] = MFMA16(pa, vb, co[dt]);
            }
        }
    }

    // ---- context write ----
    #pragma unroll
    for (int dt = 0; dt < 4; ++dt) {
        #pragma unroll
        for (int r = 0; r < 4; ++r) {
            Cg[(size_t)(wave * 16 + quad * 4 + r) * Dc + dt * 16 + l16] = co[dt][r];
        }
    }
}

extern "C" void kernel_launch(void* const* d_in, const int* in_sizes, int n_in,
                              void* d_out, int out_size, void* d_ws, size_t ws_size,
                              hipStream_t stream) {
    const float* Q    = (const float*)d_in[0];
    const float* K    = (const float*)d_in[1];
    const float* V    = (const float*)d_in[2];
    const int*   mask = (const int*)d_in[3];

    float* ctx  = (float*)d_out;                                   // [B,H,S,D]
    float* prob = (float*)d_out + (size_t)Bc * Hc * Sc * Dc;       // [B,H,S,S]

    dim3 grid(Sc / BM, Bc * Hc);
    sdpa_fused_kernel<<<grid, 256, 0, stream>>>(Q, K, V, mask, ctx, prob);
}

// Round 3
// 836.014 us; speedup vs baseline: 1.2186x; 1.0231x over previous
//
#include <hip/hip_runtime.h>
#include <math.h>

// Problem constants (B,H,S,D) = (2,16,2048,64), fp32 in, fp32 out.
constexpr int Bc = 2, Hc = 16, Sc = 2048, Dc = 64;
constexpr int BM = 64;          // q rows per block
constexpr int BN = 64;          // k rows per tile
constexpr int NKT = Sc / BN;    // 32 tiles
constexpr int TS  = BN * Dc;    // 4096 elements (8 KiB) per K/V tile buffer
constexpr float SCALE = 0.125f; // 1/sqrt(64)

typedef __bf16 bf16_t;
typedef __bf16 bf16x8 __attribute__((ext_vector_type(8)));
typedef __bf16 bf16x4 __attribute__((ext_vector_type(4)));
typedef float floatx4 __attribute__((ext_vector_type(4)));

#define MFMA16(a, b, c) __builtin_amdgcn_mfma_f32_16x16x32_bf16((a), (b), (c), 0, 0, 0)

// XOR-swizzled element index into a row-major [64][64] bf16 tile (128 B rows).
// byteoff in [0,128). Fixed-column b128 reads across rows (the MFMA fragment
// pattern) land in 8 distinct 16B slots -> <=2-way bank aliasing (free).
__device__ __forceinline__ int swzi(int row, int byteoff) {
    return row * 64 + ((byteoff ^ ((row & 7) << 4)) >> 1);
}

__global__ __launch_bounds__(256, 2)
void sdpa_fused_kernel(const float* __restrict__ Q, const float* __restrict__ K,
                       const float* __restrict__ V, const int* __restrict__ Mask,
                       float* __restrict__ CtxOut, float* __restrict__ ProbOut)
{
    // Double-buffered K (row-major) and V (transposed [d][kv]); single Ps.
    // 2*8K + 2*8K + 8K = 40960 B -> exactly 4 blocks/CU of 160 KiB.
    __shared__ bf16_t Ks[2 * TS];
    __shared__ bf16_t Vt[2 * TS];
    __shared__ bf16_t Ps[TS];        // wave w owns rows [16w, 16w+16)

    const int tid  = threadIdx.x;
    const int wave = tid >> 6;
    const int lane = tid & 63;
    const int quad = lane >> 4;
    const int l16  = lane & 15;

    const int qt    = blockIdx.x;
    const int bh    = blockIdx.y;
    const int b     = bh >> 4;       // H = 16
    const int qbase = qt * BM;

    const float* Qp = Q + ((size_t)bh * Sc + qbase) * Dc;
    const float* Kp = K + (size_t)bh * Sc * Dc;
    const float* Vp = V + (size_t)bh * Sc * Dc;
    const int*   Mp = Mask + (size_t)b * Sc * Sc;
    float* Pg = ProbOut + (size_t)bh * Sc * Sc;
    float* Cg = CtxOut + ((size_t)bh * Sc + qbase) * Dc;

    // ---- Q fragments straight from global (rows are 32B-contiguous) ----
    const float* qrow = Qp + (size_t)(wave * 16 + l16) * Dc;
    float4 qv0 = *reinterpret_cast<const float4*>(qrow + quad * 8);
    float4 qv1 = *reinterpret_cast<const float4*>(qrow + quad * 8 + 4);
    float4 qv2 = *reinterpret_cast<const float4*>(qrow + 32 + quad * 8);
    float4 qv3 = *reinterpret_cast<const float4*>(qrow + 32 + quad * 8 + 4);
    bf16x8 qa0, qa1;
    qa0[0]=(bf16_t)qv0.x; qa0[1]=(bf16_t)qv0.y; qa0[2]=(bf16_t)qv0.z; qa0[3]=(bf16_t)qv0.w;
    qa0[4]=(bf16_t)qv1.x; qa0[5]=(bf16_t)qv1.y; qa0[6]=(bf16_t)qv1.z; qa0[7]=(bf16_t)qv1.w;
    qa1[0]=(bf16_t)qv2.x; qa1[1]=(bf16_t)qv2.y; qa1[2]=(bf16_t)qv2.z; qa1[3]=(bf16_t)qv2.w;
    qa1[4]=(bf16_t)qv3.x; qa1[5]=(bf16_t)qv3.y; qa1[6]=(bf16_t)qv3.z; qa1[7]=(bf16_t)qv3.w;

    // staging coords: element i = tid + t*256 of a 64x64 tile, 4 floats each
    int srow[4], sbyte[4];
    #pragma unroll
    for (int t = 0; t < 4; ++t) {
        int i = tid + t * 256;
        srow[t]  = i >> 4;            // tile row
        sbyte[t] = (i & 15) << 3;     // bf16 byte offset in row (8B chunks)
    }
    const int vd0 = 16 * wave;        // V transpose: this thread covers d = vd0+4t+j, kv = lane

#define LOADK(kt_) { const float* Kt_ = Kp + (size_t)(kt_) * (BN * Dc);                      \
    _Pragma("unroll") for (int t = 0; t < 4; ++t)                                            \
        kreg[t] = *reinterpret_cast<const float4*>(Kt_ + srow[t] * Dc + (sbyte[t] >> 1)); }
#define WRITEK(buf_) { _Pragma("unroll") for (int t = 0; t < 4; ++t) {                       \
    bf16x4 w; w[0]=(bf16_t)kreg[t].x; w[1]=(bf16_t)kreg[t].y;                                \
              w[2]=(bf16_t)kreg[t].z; w[3]=(bf16_t)kreg[t].w;                                \
    *reinterpret_cast<bf16x4*>(&Ks[(buf_) * TS + swzi(srow[t], sbyte[t])]) = w; } }
#define LOADV(kt_) { const float* Vt_ = Vp + (size_t)(kt_) * (BN * Dc);                      \
    _Pragma("unroll") for (int t = 0; t < 4; ++t)                                            \
        vreg[t] = *reinterpret_cast<const float4*>(Vt_ + (size_t)lane * Dc + vd0 + 4 * t); }
#define WRITEV(buf_) { _Pragma("unroll") for (int t = 0; t < 4; ++t) { int d0 = vd0 + 4 * t; \
    Vt[(buf_) * TS + swzi(d0 + 0, lane * 2)] = (bf16_t)vreg[t].x;                            \
    Vt[(buf_) * TS + swzi(d0 + 1, lane * 2)] = (bf16_t)vreg[t].y;                            \
    Vt[(buf_) * TS + swzi(d0 + 2, lane * 2)] = (bf16_t)vreg[t].z;                            \
    Vt[(buf_) * TS + swzi(d0 + 3, lane * 2)] = (bf16_t)vreg[t].w; } }
#define QK_MFMA(cur_) { _Pragma("unroll") for (int nt = 0; nt < 4; ++nt) {                   \
    const int krow_ = nt * 16 + l16;                                                         \
    bf16x8 kb0 = *reinterpret_cast<const bf16x8*>(&Ks[(cur_) * TS + swzi(krow_, quad * 16)]);\
    bf16x8 kb1 = *reinterpret_cast<const bf16x8*>(&Ks[(cur_) * TS + swzi(krow_, quad * 16 + 64)]); \
    acc[nt] = MFMA16(qa0, kb0, acc[nt]);                                                     \
    acc[nt] = MFMA16(qa1, kb1, acc[nt]); } }

    float m_i[4], l_i[4];
    #pragma unroll
    for (int r = 0; r < 4; ++r) { m_i[r] = -3.0e38f; l_i[r] = 0.f; }

    const int mrow0 = qbase + wave * 16 + quad * 4;
    const int* mr[4]; float* pr[4];
    #pragma unroll
    for (int r = 0; r < 4; ++r) {
        mr[r] = Mp + (size_t)(mrow0 + r) * Sc;
        pr[r] = Pg + (size_t)(mrow0 + r) * Sc;
    }

    // ================= PASS 1: row max + sumexp (online) =================
    float4 kreg[4];
    LOADK(0);
    WRITEK(0);
    LOADK(1);
    __syncthreads();

    for (int kt = 0; kt < NKT; ++kt) {
        const int cur = kt & 1;
        const int kc  = kt * BN + l16;

        int mv[4][4];                       // issue early; consumed after MFMA
        #pragma unroll
        for (int nt = 0; nt < 4; ++nt)
            #pragma unroll
            for (int r = 0; r < 4; ++r)
                mv[nt][r] = mr[r][kc + nt * 16];

        floatx4 acc[4];
        #pragma unroll
        for (int nt = 0; nt < 4; ++nt) acc[nt] = (floatx4){0.f, 0.f, 0.f, 0.f};
        QK_MFMA(cur);

        // stage next tile into the other buffer (overlaps other waves' compute)
        if (kt + 1 < NKT) {
            WRITEK(cur ^ 1);
            if (kt + 2 < NKT) LOADK(kt + 2);
        }

        #pragma unroll
        for (int nt = 0; nt < 4; ++nt) {
            #pragma unroll
            for (int r = 0; r < 4; ++r) {
                float sv = acc[nt][r] * SCALE;
                acc[nt][r] = mv[nt][r] ? sv : -1e9f;
            }
        }
        #pragma unroll
        for (int r = 0; r < 4; ++r) {
            float mx = fmaxf(fmaxf(acc[0][r], acc[1][r]), fmaxf(acc[2][r], acc[3][r]));
            #pragma unroll
            for (int off = 1; off < 16; off <<= 1) mx = fmaxf(mx, __shfl_xor(mx, off, 64));
            float mn = fmaxf(m_i[r], mx);
            float sum = __expf(acc[0][r] - mn) + __expf(acc[1][r] - mn) +
                        __expf(acc[2][r] - mn) + __expf(acc[3][r] - mn);
            #pragma unroll
            for (int off = 1; off < 16; off <<= 1) sum += __shfl_xor(sum, off, 64);
            l_i[r] = l_i[r] * __expf(m_i[r] - mn) + sum;
            m_i[r] = mn;
        }
        __syncthreads();                    // single barrier per tile
    }

    float linv[4];
    #pragma unroll
    for (int r = 0; r < 4; ++r) linv[r] = 1.0f / l_i[r];

    floatx4 co[4];
    #pragma unroll
    for (int dt = 0; dt < 4; ++dt) co[dt] = (floatx4){0.f, 0.f, 0.f, 0.f};

    // ================= PASS 2: P = exp(s-m)/l, write P, PV MFMA =================
    float4 vreg[4];
    LOADK(0); LOADV(0);
    WRITEK(0); WRITEV(0);
    LOADK(1); LOADV(1);
    __syncthreads();

    for (int kt = 0; kt < NKT; ++kt) {
        const int cur = kt & 1;
        const int kc  = kt * BN + l16;

        int mv[4][4];
        #pragma unroll
        for (int nt = 0; nt < 4; ++nt)
            #pragma unroll
            for (int r = 0; r < 4; ++r)
                mv[nt][r] = mr[r][kc + nt * 16];

        floatx4 acc[4];
        #pragma unroll
        for (int nt = 0; nt < 4; ++nt) acc[nt] = (floatx4){0.f, 0.f, 0.f, 0.f};
        QK_MFMA(cur);

        if (kt + 1 < NKT) {
            WRITEK(cur ^ 1);
            WRITEV(cur ^ 1);
            if (kt + 2 < NKT) { LOADK(kt + 2); LOADV(kt + 2); }
        }

        #pragma unroll
        for (int nt = 0; nt < 4; ++nt) {
            #pragma unroll
            for (int r = 0; r < 4; ++r) {
                float sv = acc[nt][r] * SCALE;
                sv = mv[nt][r] ? sv : -1e9f;
                float p = __expf(sv - m_i[r]) * linv[r];
                pr[r][kc + nt * 16] = p;    // 16 lanes -> 64B contiguous
                Ps[swzi(wave * 16 + quad * 4 + r, (nt * 16 + l16) * 2)] = (bf16_t)p;
            }
        }
        // No barrier: Ps rows are wave-private; intra-wave DS order via lgkmcnt.
        #pragma unroll
        for (int ks = 0; ks < 2; ++ks) {
            bf16x8 pa = *reinterpret_cast<const bf16x8*>(
                &Ps[swzi(wave * 16 + l16, ks * 64 + quad * 16)]);
            #pragma unroll
            for (int dt = 0; dt < 4; ++dt) {
                bf16x8 vb = *reinterpret_cast<const bf16x8*>(
                    &Vt[cur * TS + swzi(dt * 16 + l16, ks * 64 + quad * 16)]);
                co[dt] = MFMA16(pa, vb, co[dt]);
            }
        }
        __syncthreads();                    // single barrier per tile
    }

    // ---- context write ----
    #pragma unroll
    for (int dt = 0; dt < 4; ++dt) {
        #pragma unroll
        for (int r = 0; r < 4; ++r) {
            Cg[(size_t)(wave * 16 + quad * 4 + r) * Dc + dt * 16 + l16] = co[dt][r];
        }
    }
#undef LOADK
#undef WRITEK
#undef LOADV
#undef WRITEV
#undef QK_MFMA
}

extern "C" void kernel_launch(void* const* d_in, const int* in_sizes, int n_in,
                              void* d_out, int out_size, void* d_ws, size_t ws_size,
                              hipStream_t stream) {
    const float* Q    = (const float*)d_in[0];
    const float* K    = (const float*)d_in[1];
    const float* V    = (const float*)d_in[2];
    const int*   mask = (const int*)d_in[3];

    float* ctx  = (float*)d_out;                                   // [B,H,S,D]
    float* prob = (float*)d_out + (size_t)Bc * Hc * Sc * Dc;       // [B,H,S,S]

    dim3 grid(Sc / BM, Bc * Hc);
    sdpa_fused_kernel<<<grid, 256, 0, stream>>>(Q, K, V, mask, ctx, prob);
}